// Round 10
// baseline (164.165 us; speedup 1.0000x reference)
//
#include <hip/hip_runtime.h>
#include <hip/hip_bf16.h>

#define M_DIM 2048   // size
#define K_DIM 2048   // prev_size
#define N_DIM 8192   // batch

#define BM 128
#define BN 256
#define BK 128            // i8 elements per K-tile (two kh halves of 64)
#define NT (K_DIM / BK)   // 16 K-tiles

typedef __attribute__((ext_vector_type(4))) int i32x4;

// async global->LDS: each lane contributes 16B; LDS dest is wave-uniform base,
// hardware writes base + lane*16 (linear).
static __device__ __forceinline__ void stage1k(const unsigned char* g, void* l) {
    __builtin_amdgcn_global_load_lds(
        (const __attribute__((address_space(1))) void*)g,
        (__attribute__((address_space(3))) void*)l, 16, 0, 0);
}

// ---- softmax over rows of Wa/Wb -> u8 quantized probs + per-row scale ------
// a_k = round(127 * exp(x_k - m)); dequant: p_k = a_k / (127 * s).
// Row scale S = 1/(127*127*s) folds both 127s for the dot-product dequant.
__global__ __launch_bounds__(256) void softmax_rows_kernel(
    const float* __restrict__ Wa, const float* __restrict__ Wb,
    unsigned char* __restrict__ Pa, unsigned char* __restrict__ Pb,
    float* __restrict__ SA, float* __restrict__ SB)
{
    const float* W = blockIdx.y ? Wb : Wa;
    unsigned char* P = blockIdx.y ? Pb : Pa;
    float* S = blockIdx.y ? SB : SA;
    const int row = blockIdx.x;
    const int t = threadIdx.x;
    const float* w = W + (size_t)row * K_DIM + t * 8;
    float4 v0 = *(const float4*)(w);
    float4 v1 = *(const float4*)(w + 4);
    float x[8] = {v0.x, v0.y, v0.z, v0.w, v1.x, v1.y, v1.z, v1.w};

    float m = x[0];
#pragma unroll
    for (int i = 1; i < 8; ++i) m = fmaxf(m, x[i]);
#pragma unroll
    for (int off = 32; off >= 1; off >>= 1) m = fmaxf(m, __shfl_xor(m, off));
    __shared__ float redm[4], reds[4];
    const int wid = t >> 6;
    if ((t & 63) == 0) redm[wid] = m;
    __syncthreads();
    m = fmaxf(fmaxf(redm[0], redm[1]), fmaxf(redm[2], redm[3]));

    float s = 0.f;
#pragma unroll
    for (int i = 0; i < 8; ++i) { x[i] = __expf(x[i] - m); s += x[i]; }
#pragma unroll
    for (int off = 32; off >= 1; off >>= 1) s += __shfl_xor(s, off);
    if ((t & 63) == 0) reds[wid] = s;
    __syncthreads();
    s = reds[0] + reds[1] + reds[2] + reds[3];

    union { unsigned char u[8]; int2 v; } pk;
#pragma unroll
    for (int i = 0; i < 8; ++i)
        pk.u[i] = (unsigned char)(int)(127.f * x[i] + 0.5f);
    *(int2*)(P + (size_t)row * K_DIM + t * 8) = pk.v;
    if (t == 0) S[row] = 1.f / (16129.f * s);
}

// ---------- table softmax (over 16) contracted with gate coeffs -> c[4][M] --
__global__ __launch_bounds__(256) void table_c_kernel(
    const float* __restrict__ TW, float4* __restrict__ C4)
{
    const int s = blockIdx.x * 256 + threadIdx.x;
    if (s >= M_DIM) return;
    float x[16];
    float m = -1e30f;
#pragma unroll
    for (int t = 0; t < 16; ++t) { x[t] = TW[t * M_DIM + s]; m = fmaxf(m, x[t]); }
    float sum = 0.f;
#pragma unroll
    for (int t = 0; t < 16; ++t) { x[t] = __expf(x[t] - m); sum += x[t]; }
    const float inv = 1.0f / sum;

    const float c0a[16] = {0,0,0,0,0,0,0,0, 1,1,1,1,1,1,1,1};
    const float cAa[16] = {0,0,1,1,0,0,1,1, -1,-1,0,0,-1,-1,0,0};
    const float cBa[16] = {0,0,0,0,1,1,1,1, -1,-1,-1,-1,0,0,0,0};
    const float cXa[16] = {0,1,-1,0,-1,0,-2,-1, 1,2,0,1,0,1,-1,0};
    float c0 = 0.f, cA = 0.f, cB = 0.f, cX = 0.f;
#pragma unroll
    for (int t = 0; t < 16; ++t) {
        const float p = x[t] * inv;
        c0 += p * c0a[t]; cA += p * cAa[t]; cB += p * cBa[t]; cX += p * cXa[t];
    }
    C4[s] = make_float4(c0, cA, cB, cX);
}

// ---- prev [K][N] f32 -> prevT [N][K] u8 (transpose + quantize x127) --------
__global__ __launch_bounds__(256) void transp_conv_kernel(
    const float* __restrict__ src, unsigned char* __restrict__ dst)
{
    __shared__ unsigned char tile[64][64];   // stride 64 -> 16B-aligned chunks
    const int n0 = blockIdx.x * 64;
    const int k0 = blockIdx.y * 64;
    const int t = threadIdx.x;
#pragma unroll
    for (int it = 0; it < 4; ++it) {
        const int lin = it * 256 + t;      // 0..1023
        const int k = lin >> 4;            // 0..63
        const int n4 = (lin & 15) * 4;     // 0..60
        float4 v = *(const float4*)(src + (size_t)(k0 + k) * N_DIM + n0 + n4);
        tile[n4 + 0][k] = (unsigned char)(int)(127.f * v.x + 0.5f);
        tile[n4 + 1][k] = (unsigned char)(int)(127.f * v.y + 0.5f);
        tile[n4 + 2][k] = (unsigned char)(int)(127.f * v.z + 0.5f);
        tile[n4 + 3][k] = (unsigned char)(int)(127.f * v.w + 0.5f);
    }
    __syncthreads();
    const int n = t >> 2;                  // 0..63
    const int k16 = (t & 3) * 16;          // 0..48
    int4 v = *(const int4*)&tile[n][k16];
    *(int4*)(dst + (size_t)(n0 + n) * K_DIM + k0 + k16) = v;
}

// ---- dual i8 GEMM: A from global (L2-resident), P via LDS pipeline ---------
// LDS = sPt only (64 KB). P staging/swizzle/read identical to the verified
// R9 kernel (sigma(r)=(r>>1)&3, conflicts = 0). A-fragments (Pa/Pb, 8 MB,
// L2/L3-fit) load global->VGPR with the same lane mapping the LDS path used:
// row = lane&15, k-offset = (lane>>4)*16; per instr 16 distinct 64B lines,
// 4 lanes/line; 4 waves (same wr) share addresses -> L1 reuse.
//
// Register sets aA/aB/fp are reloaded IN PLACE (static names, WAR-ordered by
// compiler): aA used ph1(kh0)/ph3(kh1), reloaded at end of ph1 and ph3;
// aB used ph2/ph4, reloaded end of ph2/ph4; fp used ph1-2/ph3-4, re-read
// end of ph2 (kh1) and ph4 (next tile kh0).
//
// vmcnt ledger (mixed FIFO: A-loads + stage1k, in-order completion):
// per kt issues ph1:A4, ph2:A4+S2(P(t+2)kh0), ph3:A4, ph4:A4+S2(P(t+2)kh1),
// then guard vmcnt(10) = drains all but {ph3 A4, ph4 A4+S2}. This proves
// P(t+1)kh0 (issued ph2(kt-1), 11th-newest at guard(kt-1)) complete before
// its ph4(kt) read, and P(t)kh1 before its ph2 read. Prologue: 8 stages +
// 8 A-loads, vmcnt(8) drains all P(0)+P(1). WAR on LDS regions: each
// region's last ds_read is consumed by MFMA (compiler lgkm wait) before the
// barrier that precedes the overwriting stage issue.

#define MFMA8(ACC, FA, FP, MI0)                                                \
    _Pragma("unroll") for (int mi = (MI0); mi < (MI0) + 2; ++mi)               \
    _Pragma("unroll") for (int ni = 0; ni < 4; ++ni)                           \
        ACC[mi][ni] = __builtin_amdgcn_mfma_i32_16x16x64_i8(                   \
            FA[mi], FP[ni], ACC[mi][ni], 0, 0, 0);

#define LOAD_FRAGS(SET, GP, T, KH)                                             \
    _Pragma("unroll") for (int i = 0; i < 4; ++i)                              \
        SET[i] = *(const i32x4*)((GP) + (size_t)i * 16 * K_DIM +               \
                                 (size_t)(T) * BK + (KH) * 64);

#define RD_P(BUF, KH)                                                          \
    _Pragma("unroll") for (int i = 0; i < 4; ++i)                              \
        fp[i] = *(const i32x4*)((const char*)&sPt[BUF][KH][0][0] + roP + i * 1024);

#define STAGE_P(T, KH) do { if ((T) < NT) {                                    \
    const int b_ = (T) & 1;                                                    \
    const size_t o_ = (size_t)(T) * BK + (KH) * 64;                            \
    stage1k(gPt0 + o_, &sPt[b_][KH][wid * 16][0]);                             \
    stage1k(gPt1 + o_, &sPt[b_][KH][128 + wid * 16][0]); } } while (0)

__global__ __launch_bounds__(512, 2) void logic_gemm_kernel(
    const unsigned char* __restrict__ Pa,   // [M][K] u8
    const unsigned char* __restrict__ Pb,   // [M][K] u8
    const unsigned char* __restrict__ Pt,   // prevT [N][K] u8
    const float4* __restrict__ C4,          // [M]
    const float* __restrict__ SA,           // [M] dequant scales
    const float* __restrict__ SB,           // [M]
    float* __restrict__ out)                // [M][N]
{
    __shared__ unsigned char sPt[2][2][256][64];   // 64 KB

    const int m0 = blockIdx.y * BM;
    const int n0 = blockIdx.x * BN;
    const int t = threadIdx.x;
    const int wid = t >> 6, lane = t & 63;
    const int wr = wid >> 2, wc = wid & 3;   // 2M x 4N waves, 64x64 out each
    const int lq = lane >> 4, lr = lane & 15;

    // P staging: lane -> region row (lane>>2), pre-swizzled source col (bytes)
    const int srow = lane >> 2;                               // 0..15
    const int scol = (((lane & 3) ^ ((lane >> 3) & 3)) << 4); // {0,16,32,48} B
    const unsigned char* gPt0 = Pt + (size_t)(n0 + wid * 16 + srow) * K_DIM + scol;
    const unsigned char* gPt1 = gPt0 + (size_t)128 * K_DIM;

    // A/B direct-global fragment base (per-lane): row = wr*64 + lr, k = lq*16
    const unsigned char* gA = Pa + (size_t)(m0 + wr * 64 + lr) * K_DIM + lq * 16;
    const unsigned char* gB = Pb + (size_t)(m0 + wr * 64 + lr) * K_DIM + lq * 16;

    // P ds_read byte offsets (swizzled): row*64 + 16*(lq ^ ((row>>1)&3))
    const int cswz = (lq ^ ((lr >> 1) & 3)) << 4;
    const int roP = (wc * 64 + lr) * 64 + cswz;   // within [256][64B] region

    i32x4 accA[4][4] = {};
    i32x4 accB[4][4] = {};
    i32x4 aA[4], aB[4], fp[4];

    // prologue: P(0),P(1) staged (8 calls); A kh0(0) loaded; drain all stages.
    STAGE_P(0, 0); STAGE_P(0, 1); STAGE_P(1, 0); STAGE_P(1, 1);
    LOAD_FRAGS(aA, gA, 0, 0);
    LOAD_FRAGS(aB, gB, 0, 0);
    asm volatile("s_waitcnt vmcnt(8)" ::: "memory");
    __builtin_amdgcn_s_barrier();
    RD_P(0, 0);

    for (int kt = 0; kt < NT; ++kt) {
        const int buf = kt & 1;

        // -------- phase 1: accA x kh0 (aA, fp) --------
        __builtin_amdgcn_s_setprio(1);
        MFMA8(accA, aA, fp, 0);
        MFMA8(accA, aA, fp, 2);
        __builtin_amdgcn_s_setprio(0);
        LOAD_FRAGS(aA, gA, kt, 1);          // kh1 of this tile
        __builtin_amdgcn_s_barrier();

        // -------- phase 2: accB x kh0 (aB, fp) --------
        __builtin_amdgcn_s_setprio(1);
        MFMA8(accB, aB, fp, 0);
        MFMA8(accB, aB, fp, 2);
        __builtin_amdgcn_s_setprio(0);
        LOAD_FRAGS(aB, gB, kt, 1);
        RD_P(buf, 1);                        // P kh1 (staged >= 2 kt ago)
        STAGE_P(kt + 2, 0);                  // overwrites sPt[buf][0]
        __builtin_amdgcn_s_barrier();

        // -------- phase 3: accA x kh1 (aA, fp) --------
        __builtin_amdgcn_s_setprio(1);
        MFMA8(accA, aA, fp, 0);
        MFMA8(accA, aA, fp, 2);
        __builtin_amdgcn_s_setprio(0);
        if (kt + 1 < NT) LOAD_FRAGS(aA, gA, kt + 1, 0);
        __builtin_amdgcn_s_barrier();

        // -------- phase 4: accB x kh1 (aB, fp) --------
        __builtin_amdgcn_s_setprio(1);
        MFMA8(accB, aB, fp, 0);
        MFMA8(accB, aB, fp, 2);
        __builtin_amdgcn_s_setprio(0);
        if (kt + 1 < NT) LOAD_FRAGS(aB, gB, kt + 1, 0);
        RD_P(buf ^ 1, 0);                    // next tile kh0 (guard-proven)
        STAGE_P(kt + 2, 1);                  // overwrites sPt[buf][1]
        asm volatile("s_waitcnt vmcnt(10)" ::: "memory");
        __builtin_amdgcn_s_barrier();
    }

    // epilogue: dequant + gate polynomial
#pragma unroll
    for (int mi = 0; mi < 4; ++mi) {
#pragma unroll
        for (int i = 0; i < 4; ++i) {
            const int row = m0 + wr * 64 + mi * 16 + lq * 4 + i;
            const float4 c = C4[row];
            const float sa = SA[row];
            const float sb = SB[row];
#pragma unroll
            for (int ni = 0; ni < 4; ++ni) {
                const int col = n0 + wc * 64 + ni * 16 + lr;
                const float Av = (float)accA[mi][ni][i] * sa;
                const float Bv = (float)accB[mi][ni][i] * sb;
                out[(size_t)row * N_DIM + col] = c.x + c.y * Av + c.z * Bv + c.w * Av * Bv;
            }
        }
    }
}

extern "C" void kernel_launch(void* const* d_in, const int* in_sizes, int n_in,
                              void* d_out, int out_size, void* d_ws, size_t ws_size,
                              hipStream_t stream) {
    const float* prev = (const float*)d_in[0];   // [2048][8192]
    const float* Wa   = (const float*)d_in[1];   // [2048][2048]
    const float* Wb   = (const float*)d_in[2];   // [2048][2048]
    const float* TW   = (const float*)d_in[3];   // [16][2048]
    float* out = (float*)d_out;                  // [2048][8192]

    char* ws = (char*)d_ws;
    unsigned char* Pa = (unsigned char*)(ws);                       //  4 MiB
    unsigned char* Pb = (unsigned char*)(ws + (size_t)(4u << 20));  //  4 MiB
    unsigned char* Pt = (unsigned char*)(ws + (size_t)(8u << 20));  // 16 MiB
    float4* C4 = (float4*)(ws + (size_t)(24u << 20));               // 32 KiB
    float*  SA = (float*)(ws + (size_t)(24u << 20) + (32u << 10));  //  8 KiB
    float*  SB = (float*)(ws + (size_t)(24u << 20) + (64u << 10));  //  8 KiB

    softmax_rows_kernel<<<dim3(2048, 2), 256, 0, stream>>>(Wa, Wb, Pa, Pb, SA, SB);
    table_c_kernel<<<dim3(8), 256, 0, stream>>>(TW, C4);
    transp_conv_kernel<<<dim3(N_DIM / 64, K_DIM / 64), 256, 0, stream>>>(prev, Pt);
    logic_gemm_kernel<<<dim3(N_DIM / BN, M_DIM / BM), 512, 0, stream>>>(Pa, Pb, Pt, C4, SA, SB, out);
}

// Round 11
// 104.584 us; speedup vs baseline: 1.5697x; 1.5697x over previous
//
#include <hip/hip_runtime.h>
#include <hip/hip_bf16.h>

#define M_DIM 2048   // size
#define K_DIM 2048   // prev_size
#define N_DIM 8192   // batch

#define BM 128
#define BN 128
#define BK 64             // i8 elements (bytes) per K-tile
#define NT (K_DIM / BK)   // 32 K-tiles

typedef __attribute__((ext_vector_type(4))) int i32x4;

// async global->LDS: each lane contributes 16B; LDS dest is wave-uniform base,
// hardware writes base + lane*16 (linear).
static __device__ __forceinline__ void stage1k(const unsigned char* g, void* l) {
    __builtin_amdgcn_global_load_lds(
        (const __attribute__((address_space(1))) void*)g,
        (__attribute__((address_space(3))) void*)l, 16, 0, 0);
}

// ---- softmax over rows of Wa/Wb -> u8 quantized probs + per-row scale ------
// a_k = round(127 * exp(x_k - m)); dequant: p_k = a_k / (127 * s).
// Row scale S = 1/(127*127*s) folds both 127s for the dot-product dequant.
__global__ __launch_bounds__(256) void softmax_rows_kernel(
    const float* __restrict__ Wa, const float* __restrict__ Wb,
    unsigned char* __restrict__ Pa, unsigned char* __restrict__ Pb,
    float* __restrict__ SA, float* __restrict__ SB)
{
    const float* W = blockIdx.y ? Wb : Wa;
    unsigned char* P = blockIdx.y ? Pb : Pa;
    float* S = blockIdx.y ? SB : SA;
    const int row = blockIdx.x;
    const int t = threadIdx.x;
    const float* w = W + (size_t)row * K_DIM + t * 8;
    float4 v0 = *(const float4*)(w);
    float4 v1 = *(const float4*)(w + 4);
    float x[8] = {v0.x, v0.y, v0.z, v0.w, v1.x, v1.y, v1.z, v1.w};

    float m = x[0];
#pragma unroll
    for (int i = 1; i < 8; ++i) m = fmaxf(m, x[i]);
#pragma unroll
    for (int off = 32; off >= 1; off >>= 1) m = fmaxf(m, __shfl_xor(m, off));
    __shared__ float redm[4], reds[4];
    const int wid = t >> 6;
    if ((t & 63) == 0) redm[wid] = m;
    __syncthreads();
    m = fmaxf(fmaxf(redm[0], redm[1]), fmaxf(redm[2], redm[3]));

    float s = 0.f;
#pragma unroll
    for (int i = 0; i < 8; ++i) { x[i] = __expf(x[i] - m); s += x[i]; }
#pragma unroll
    for (int off = 32; off >= 1; off >>= 1) s += __shfl_xor(s, off);
    if ((t & 63) == 0) reds[wid] = s;
    __syncthreads();
    s = reds[0] + reds[1] + reds[2] + reds[3];

    union { unsigned char u[8]; int2 v; } pk;
#pragma unroll
    for (int i = 0; i < 8; ++i)
        pk.u[i] = (unsigned char)(int)(127.f * x[i] + 0.5f);
    *(int2*)(P + (size_t)row * K_DIM + t * 8) = pk.v;
    if (t == 0) S[row] = 1.f / (16129.f * s);
}

// ---------- table softmax (over 16) contracted with gate coeffs -> c[4][M] --
__global__ __launch_bounds__(256) void table_c_kernel(
    const float* __restrict__ TW, float4* __restrict__ C4)
{
    const int s = blockIdx.x * 256 + threadIdx.x;
    if (s >= M_DIM) return;
    float x[16];
    float m = -1e30f;
#pragma unroll
    for (int t = 0; t < 16; ++t) { x[t] = TW[t * M_DIM + s]; m = fmaxf(m, x[t]); }
    float sum = 0.f;
#pragma unroll
    for (int t = 0; t < 16; ++t) { x[t] = __expf(x[t] - m); sum += x[t]; }
    const float inv = 1.0f / sum;

    const float c0a[16] = {0,0,0,0,0,0,0,0, 1,1,1,1,1,1,1,1};
    const float cAa[16] = {0,0,1,1,0,0,1,1, -1,-1,0,0,-1,-1,0,0};
    const float cBa[16] = {0,0,0,0,1,1,1,1, -1,-1,-1,-1,0,0,0,0};
    const float cXa[16] = {0,1,-1,0,-1,0,-2,-1, 1,2,0,1,0,1,-1,0};
    float c0 = 0.f, cA = 0.f, cB = 0.f, cX = 0.f;
#pragma unroll
    for (int t = 0; t < 16; ++t) {
        const float p = x[t] * inv;
        c0 += p * c0a[t]; cA += p * cAa[t]; cB += p * cBa[t]; cX += p * cXa[t];
    }
    C4[s] = make_float4(c0, cA, cB, cX);
}

// ---- prev [K][N] f32 -> prevT [N][K] u8 (transpose + quantize x127) --------
__global__ __launch_bounds__(256) void transp_conv_kernel(
    const float* __restrict__ src, unsigned char* __restrict__ dst)
{
    __shared__ unsigned char tile[64][64];
    const int n0 = blockIdx.x * 64;
    const int k0 = blockIdx.y * 64;
    const int t = threadIdx.x;
#pragma unroll
    for (int it = 0; it < 4; ++it) {
        const int lin = it * 256 + t;      // 0..1023
        const int k = lin >> 4;            // 0..63
        const int n4 = (lin & 15) * 4;     // 0..60
        float4 v = *(const float4*)(src + (size_t)(k0 + k) * N_DIM + n0 + n4);
        tile[n4 + 0][k] = (unsigned char)(int)(127.f * v.x + 0.5f);
        tile[n4 + 1][k] = (unsigned char)(int)(127.f * v.y + 0.5f);
        tile[n4 + 2][k] = (unsigned char)(int)(127.f * v.z + 0.5f);
        tile[n4 + 3][k] = (unsigned char)(int)(127.f * v.w + 0.5f);
    }
    __syncthreads();
    const int n = t >> 2;                  // 0..63
    const int k16 = (t & 3) * 16;          // 0..48
    int4 v = *(const int4*)&tile[n][k16];
    *(int4*)(dst + (size_t)(n0 + n) * K_DIM + k0 + k16) = v;
}

// ---- dual i8 GEMM, 128x128 tile, 4 waves, 2 blocks/CU ----------------------
// All components verified in R9 (i8 quant, sigma(r)=(r>>1)&3 swizzle with
// pre-swizzled global source, stage1k, 16x16x64 i8 MFMA, epilogue): only the
// blocking changes. LDS 48 KB -> 2 resident blocks/CU = two INDEPENDENT
// barrier domains; block A's MFMA overlaps block B's LDS reads/stages and
// vmcnt drain (m97/m114 mechanism) - R9's 128 KB/1-block serialized the
// MFMA and LDS pipes (sum-behavior, 41% MfmaUtil).
//
// Per kt (K=64): stage 6x1KB for kt+1 into buf^1 (WAR-safe: buf^1's reads
// were consumed by kt-1's MFMAs before kt-1's barrier); read 12 b128 from
// buf; 32 MFMA; vmcnt(0) drains this wave's 6 stages (issued ~1300 cyc
// earlier -> near-zero stall, and overlapped by sibling block); barrier.

#define MFMA8(ACC, FA, FP, MI0)                                                \
    _Pragma("unroll") for (int mi = (MI0); mi < (MI0) + 2; ++mi)               \
    _Pragma("unroll") for (int ni = 0; ni < 4; ++ni)                           \
        ACC[mi][ni] = __builtin_amdgcn_mfma_i32_16x16x64_i8(                   \
            FA[mi], FP[ni], ACC[mi][ni], 0, 0, 0);

#define STAGE_ALL(T) do { const int b_ = (T) & 1;                              \
    const size_t o_ = (size_t)(T) * BK;                                        \
    stage1k(gPa + o_,               &sPa[b_][wid * 32][0]);                    \
    stage1k(gPa + o_ + 16 * K_DIM,  &sPa[b_][wid * 32 + 16][0]);               \
    stage1k(gPb + o_,               &sPb[b_][wid * 32][0]);                    \
    stage1k(gPb + o_ + 16 * K_DIM,  &sPb[b_][wid * 32 + 16][0]);               \
    stage1k(gPt + o_,               &sPt[b_][wid * 32][0]);                    \
    stage1k(gPt + o_ + 16 * K_DIM,  &sPt[b_][wid * 32 + 16][0]); } while (0)

__global__ __launch_bounds__(256, 2) void logic_gemm_kernel(
    const unsigned char* __restrict__ Pa,   // [M][K] u8
    const unsigned char* __restrict__ Pb,   // [M][K] u8
    const unsigned char* __restrict__ Pt,   // prevT [N][K] u8
    const float4* __restrict__ C4,          // [M]
    const float* __restrict__ SA,           // [M] dequant scales
    const float* __restrict__ SB,           // [M]
    float* __restrict__ out)                // [M][N]
{
    __shared__ unsigned char sPa[2][128][64];   // 16 KB
    __shared__ unsigned char sPb[2][128][64];   // 16 KB
    __shared__ unsigned char sPt[2][128][64];   // 16 KB

    const int m0 = blockIdx.y * BM;
    const int n0 = blockIdx.x * BN;
    const int t = threadIdx.x;
    const int wid = t >> 6, lane = t & 63;
    const int wr = wid >> 1, wc = wid & 1;   // 2x2 waves, 64x64 out each
    const int lq = lane >> 4, lr = lane & 15;

    // staging: lane -> region row (lane>>2), pre-swizzled source col (bytes)
    const int srow = lane >> 2;                               // 0..15
    const int scol = (((lane & 3) ^ ((lane >> 3) & 3)) << 4); // {0,16,32,48} B
    const unsigned char* gPa = Pa + (size_t)(m0 + wid * 32 + srow) * K_DIM + scol;
    const unsigned char* gPb = Pb + (size_t)(m0 + wid * 32 + srow) * K_DIM + scol;
    const unsigned char* gPt = Pt + (size_t)(n0 + wid * 32 + srow) * K_DIM + scol;

    // ds_read byte offsets (swizzled): row*64 + 16*(lq ^ ((row>>1)&3))
    const int cswz = (lq ^ ((lr >> 1) & 3)) << 4;
    const int roA = (wr * 64 + lr) * 64 + cswz;   // within [128][64B] region
    const int roP = (wc * 64 + lr) * 64 + cswz;

    i32x4 accA[4][4] = {};
    i32x4 accB[4][4] = {};
    i32x4 fa[4], fb[4], fp[4];

    // prologue: stage tile 0, drain, publish.
    STAGE_ALL(0);
    asm volatile("s_waitcnt vmcnt(0)" ::: "memory");
    __builtin_amdgcn_s_barrier();

    for (int kt = 0; kt < NT; ++kt) {
        const int buf = kt & 1;
        const char* bA = (const char*)&sPa[buf][0][0];
        const char* bB = (const char*)&sPb[buf][0][0];
        const char* bP = (const char*)&sPt[buf][0][0];

        if (kt + 1 < NT) STAGE_ALL(kt + 1);   // into buf^1 (WAR-safe)

#pragma unroll
        for (int i = 0; i < 4; ++i) fa[i] = *(const i32x4*)(bA + roA + i * 1024);
#pragma unroll
        for (int i = 0; i < 4; ++i) fp[i] = *(const i32x4*)(bP + roP + i * 1024);
#pragma unroll
        for (int i = 0; i < 4; ++i) fb[i] = *(const i32x4*)(bB + roA + i * 1024);

        __builtin_amdgcn_s_setprio(1);
        MFMA8(accA, fa, fp, 0);
        MFMA8(accA, fa, fp, 2);
        MFMA8(accB, fb, fp, 0);
        MFMA8(accB, fb, fp, 2);
        __builtin_amdgcn_s_setprio(0);

        if (kt + 1 < NT) asm volatile("s_waitcnt vmcnt(0)" ::: "memory");
        __builtin_amdgcn_s_barrier();
    }

    // epilogue: dequant + gate polynomial
#pragma unroll
    for (int mi = 0; mi < 4; ++mi) {
#pragma unroll
        for (int i = 0; i < 4; ++i) {
            const int row = m0 + wr * 64 + mi * 16 + lq * 4 + i;
            const float4 c = C4[row];
            const float sa = SA[row];
            const float sb = SB[row];
#pragma unroll
            for (int ni = 0; ni < 4; ++ni) {
                const int col = n0 + wc * 64 + ni * 16 + lr;
                const float Av = (float)accA[mi][ni][i] * sa;
                const float Bv = (float)accB[mi][ni][i] * sb;
                out[(size_t)row * N_DIM + col] = c.x + c.y * Av + c.z * Bv + c.w * Av * Bv;
            }
        }
    }
}

extern "C" void kernel_launch(void* const* d_in, const int* in_sizes, int n_in,
                              void* d_out, int out_size, void* d_ws, size_t ws_size,
                              hipStream_t stream) {
    const float* prev = (const float*)d_in[0];   // [2048][8192]
    const float* Wa   = (const float*)d_in[1];   // [2048][2048]
    const float* Wb   = (const float*)d_in[2];   // [2048][2048]
    const float* TW   = (const float*)d_in[3];   // [16][2048]
    float* out = (float*)d_out;                  // [2048][8192]

    char* ws = (char*)d_ws;
    unsigned char* Pa = (unsigned char*)(ws);                       //  4 MiB
    unsigned char* Pb = (unsigned char*)(ws + (size_t)(4u << 20));  //  4 MiB
    unsigned char* Pt = (unsigned char*)(ws + (size_t)(8u << 20));  // 16 MiB
    float4* C4 = (float4*)(ws + (size_t)(24u << 20));               // 32 KiB
    float*  SA = (float*)(ws + (size_t)(24u << 20) + (32u << 10));  //  8 KiB
    float*  SB = (float*)(ws + (size_t)(24u << 20) + (64u << 10));  //  8 KiB

    softmax_rows_kernel<<<dim3(2048, 2), 256, 0, stream>>>(Wa, Wb, Pa, Pb, SA, SB);
    table_c_kernel<<<dim3(8), 256, 0, stream>>>(TW, C4);
    transp_conv_kernel<<<dim3(N_DIM / 64, K_DIM / 64), 256, 0, stream>>>(prev, Pt);
    logic_gemm_kernel<<<dim3(N_DIM / BN, M_DIM / BM), 256, 0, stream>>>(Pa, Pb, Pt, C4, SA, SB, out);
}

// Round 12
// 89.528 us; speedup vs baseline: 1.8337x; 1.1682x over previous
//
#include <hip/hip_runtime.h>
#include <hip/hip_bf16.h>

#define M_DIM 2048   // size
#define K_DIM 2048   // prev_size
#define N_DIM 8192   // batch

#define BM 128
#define BN 256
#define BK 128            // i8 elements per K-tile (two kh halves of 64)
#define NT (K_DIM / BK)   // 16 K-tiles

typedef __attribute__((ext_vector_type(4))) int i32x4;

// async global->LDS: each lane contributes 16B; LDS dest is wave-uniform base,
// hardware writes base + lane*16 (linear).
static __device__ __forceinline__ void stage1k(const unsigned char* g, void* l) {
    __builtin_amdgcn_global_load_lds(
        (const __attribute__((address_space(1))) void*)g,
        (__attribute__((address_space(3))) void*)l, 16, 0, 0);
}

// ---- softmax over rows of Wa/Wb -> u8 quantized probs + per-row scale ------
// a_k = round(127 * exp(x_k - m)); dequant: p_k = a_k / (127 * s).
// Row scale S = 1/(127*127*s) folds both 127s for the dot-product dequant.
__global__ __launch_bounds__(256) void softmax_rows_kernel(
    const float* __restrict__ Wa, const float* __restrict__ Wb,
    unsigned char* __restrict__ Pa, unsigned char* __restrict__ Pb,
    float* __restrict__ SA, float* __restrict__ SB)
{
    const float* W = blockIdx.y ? Wb : Wa;
    unsigned char* P = blockIdx.y ? Pb : Pa;
    float* S = blockIdx.y ? SB : SA;
    const int row = blockIdx.x;
    const int t = threadIdx.x;
    const float* w = W + (size_t)row * K_DIM + t * 8;
    float4 v0 = *(const float4*)(w);
    float4 v1 = *(const float4*)(w + 4);
    float x[8] = {v0.x, v0.y, v0.z, v0.w, v1.x, v1.y, v1.z, v1.w};

    float m = x[0];
#pragma unroll
    for (int i = 1; i < 8; ++i) m = fmaxf(m, x[i]);
#pragma unroll
    for (int off = 32; off >= 1; off >>= 1) m = fmaxf(m, __shfl_xor(m, off));
    __shared__ float redm[4], reds[4];
    const int wid = t >> 6;
    if ((t & 63) == 0) redm[wid] = m;
    __syncthreads();
    m = fmaxf(fmaxf(redm[0], redm[1]), fmaxf(redm[2], redm[3]));

    float s = 0.f;
#pragma unroll
    for (int i = 0; i < 8; ++i) { x[i] = __expf(x[i] - m); s += x[i]; }
#pragma unroll
    for (int off = 32; off >= 1; off >>= 1) s += __shfl_xor(s, off);
    if ((t & 63) == 0) reds[wid] = s;
    __syncthreads();
    s = reds[0] + reds[1] + reds[2] + reds[3];

    union { unsigned char u[8]; int2 v; } pk;
#pragma unroll
    for (int i = 0; i < 8; ++i)
        pk.u[i] = (unsigned char)(int)(127.f * x[i] + 0.5f);
    *(int2*)(P + (size_t)row * K_DIM + t * 8) = pk.v;
    if (t == 0) S[row] = 1.f / (16129.f * s);
}

// ---------- table softmax (over 16) contracted with gate coeffs -> c[4][M] --
__global__ __launch_bounds__(256) void table_c_kernel(
    const float* __restrict__ TW, float4* __restrict__ C4)
{
    const int s = blockIdx.x * 256 + threadIdx.x;
    if (s >= M_DIM) return;
    float x[16];
    float m = -1e30f;
#pragma unroll
    for (int t = 0; t < 16; ++t) { x[t] = TW[t * M_DIM + s]; m = fmaxf(m, x[t]); }
    float sum = 0.f;
#pragma unroll
    for (int t = 0; t < 16; ++t) { x[t] = __expf(x[t] - m); sum += x[t]; }
    const float inv = 1.0f / sum;

    const float c0a[16] = {0,0,0,0,0,0,0,0, 1,1,1,1,1,1,1,1};
    const float cAa[16] = {0,0,1,1,0,0,1,1, -1,-1,0,0,-1,-1,0,0};
    const float cBa[16] = {0,0,0,0,1,1,1,1, -1,-1,-1,-1,0,0,0,0};
    const float cXa[16] = {0,1,-1,0,-1,0,-2,-1, 1,2,0,1,0,1,-1,0};
    float c0 = 0.f, cA = 0.f, cB = 0.f, cX = 0.f;
#pragma unroll
    for (int t = 0; t < 16; ++t) {
        const float p = x[t] * inv;
        c0 += p * c0a[t]; cA += p * cAa[t]; cB += p * cBa[t]; cX += p * cXa[t];
    }
    C4[s] = make_float4(c0, cA, cB, cX);
}

// ---- prev [K][N] f32 -> prevT [N][K] u8 (transpose + quantize x127) --------
// v2: 4x4 micro-block per thread. Packs 4 k-bytes into one u32 LDS write
// (4 writes vs 16 scalar u8), tile rows padded to 80 B. Bank audit: writes
// 2-way (bank = 16*((l&15)&1) + 20i + (l>>4) covers 32 banks over 64 lanes),
// int4 reads 2-way (20q+4r mod 32, each hit exactly 2x) - both free (m136).
// Old version was a 16-way write conflict (bank = 16j for all lanes).
__global__ __launch_bounds__(256) void transp_conv_kernel(
    const float* __restrict__ src, unsigned char* __restrict__ dst)
{
    __shared__ unsigned char tile[64][80];
    const int n0 = blockIdx.x * 64;
    const int k0 = blockIdx.y * 64;
    const int t = threadIdx.x;
    const int kb = (t >> 4) * 4;   // k micro-block base
    const int nb = (t & 15) * 4;   // n micro-block base

    unsigned int pk0 = 0, pk1 = 0, pk2 = 0, pk3 = 0;
#pragma unroll
    for (int j = 0; j < 4; ++j) {
        float4 v = *(const float4*)(src + (size_t)(k0 + kb + j) * N_DIM + n0 + nb);
        pk0 |= (unsigned int)(unsigned char)(int)(127.f * v.x + 0.5f) << (8 * j);
        pk1 |= (unsigned int)(unsigned char)(int)(127.f * v.y + 0.5f) << (8 * j);
        pk2 |= (unsigned int)(unsigned char)(int)(127.f * v.z + 0.5f) << (8 * j);
        pk3 |= (unsigned int)(unsigned char)(int)(127.f * v.w + 0.5f) << (8 * j);
    }
    *(unsigned int*)&tile[nb + 0][kb] = pk0;
    *(unsigned int*)&tile[nb + 1][kb] = pk1;
    *(unsigned int*)&tile[nb + 2][kb] = pk2;
    *(unsigned int*)&tile[nb + 3][kb] = pk3;
    __syncthreads();
    const int n = t >> 2;                  // 0..63
    const int k16 = (t & 3) * 16;          // 0..48
    int4 v = *(const int4*)&tile[n][k16];
    *(int4*)(dst + (size_t)(n0 + n) * K_DIM + k0 + k16) = v;
}

// ------------- dual i8 GEMM, pipelined 4-phase schedule + gate epilogue -----
// Champion R9 kernel, verbatim (67 us GEMM, MfmaUtil 41%, 0 bank conflicts).
// LDS regions [128 or 256 rows][64 B], sigma(r)=(r>>1)&3 16B-slot swizzle
// (write: pre-swizzled global col; read: same XOR). Tile covers K=128 i8.
// MFMA: mfma_i32_16x16x64_i8; C/D layout dtype-independent (m121).
//
// Stage pairs (2 loads each) for tile T:
//   A(T)@ph2(T-2), B(T)@ph3(T-2), C(T)@ph4(T-2), D(T)@ph1(T-1)
// Guards: vmcnt(6) at ph1 (drains D(t)), vmcnt(6) at ph3 (drains A,B(t+1)).
// Tail (kt >= NT-2): vmcnt(0).

#define MFMA8(ACC, FA, FP, MI0)                                                \
    _Pragma("unroll") for (int mi = (MI0); mi < (MI0) + 2; ++mi)               \
    _Pragma("unroll") for (int ni = 0; ni < 4; ++ni)                           \
        ACC[mi][ni] = __builtin_amdgcn_mfma_i32_16x16x64_i8(                   \
            FA[mi], FP[ni], ACC[mi][ni], 0, 0, 0);

#define STAGE_A(T) do { const int b_ = (T) & 1; const size_t o_ = (size_t)(T) * BK; \
    stage1k(gPa + o_,  &sPa[b_][0][wid * 16][0]);                              \
    stage1k(gPt0 + o_, &sPt[b_][0][wid * 16][0]); } while (0)
#define STAGE_B(T) do { const int b_ = (T) & 1; const size_t o_ = (size_t)(T) * BK; \
    stage1k(gPt1 + o_, &sPt[b_][0][128 + wid * 16][0]);                        \
    stage1k(gPb + o_,  &sPb[b_][0][wid * 16][0]); } while (0)
#define STAGE_C(T) do { const int b_ = (T) & 1; const size_t o_ = (size_t)(T) * BK + 64; \
    stage1k(gPa + o_,  &sPa[b_][1][wid * 16][0]);                              \
    stage1k(gPt0 + o_, &sPt[b_][1][wid * 16][0]); } while (0)
#define STAGE_D(T) do { const int b_ = (T) & 1; const size_t o_ = (size_t)(T) * BK + 64; \
    stage1k(gPt1 + o_, &sPt[b_][1][128 + wid * 16][0]);                        \
    stage1k(gPb + o_,  &sPb[b_][1][wid * 16][0]); } while (0)

__global__ __launch_bounds__(512, 2) void logic_gemm_kernel(
    const unsigned char* __restrict__ Pa,   // [M][K] u8
    const unsigned char* __restrict__ Pb,   // [M][K] u8
    const unsigned char* __restrict__ Pt,   // prevT [N][K] u8
    const float4* __restrict__ C4,          // [M]
    const float* __restrict__ SA,           // [M] dequant scales
    const float* __restrict__ SB,           // [M]
    float* __restrict__ out)                // [M][N]
{
    __shared__ unsigned char sPa[2][2][128][64];   // 32 KB
    __shared__ unsigned char sPb[2][2][128][64];   // 32 KB
    __shared__ unsigned char sPt[2][2][256][64];   // 64 KB

    const int m0 = blockIdx.y * BM;
    const int n0 = blockIdx.x * BN;
    const int t = threadIdx.x;
    const int wid = t >> 6, lane = t & 63;
    const int wr = wid >> 2, wc = wid & 3;   // 2M x 4N waves, 64x64 out each
    const int lq = lane >> 4, lr = lane & 15;

    // staging: lane -> region row (lane>>2), pre-swizzled source col (bytes)
    const int srow = lane >> 2;                               // 0..15
    const int scol = (((lane & 3) ^ ((lane >> 3) & 3)) << 4); // {0,16,32,48} B
    const unsigned char* gPa  = Pa + (size_t)(m0 + wid * 16 + srow) * K_DIM + scol;
    const unsigned char* gPb  = Pb + (size_t)(m0 + wid * 16 + srow) * K_DIM + scol;
    const unsigned char* gPt0 = Pt + (size_t)(n0 + wid * 16 + srow) * K_DIM + scol;
    const unsigned char* gPt1 = gPt0 + (size_t)128 * K_DIM;

    // ds_read byte offsets (swizzled): row*64 + 16*(lq ^ sigma(row)),
    // sigma(r) = (r>>1)&3 -> conflict-free (verified R4/R5/R7/R9)
    const int cswz = (lq ^ ((lr >> 1) & 3)) << 4;
    const int roA = (wr * 64 + lr) * 64 + cswz;   // within [128][64B] region
    const int roP = (wc * 64 + lr) * 64 + cswz;   // within [256][64B] region

    i32x4 accA[4][4] = {};
    i32x4 accB[4][4] = {};
    i32x4 fX0[4], fX1[4], fpA[4], fpB[4];

    // prologue: A,B,C,D(0), A,B,C(1) = 14 loads; drain first 4 (A,B(0));
    // barrier; pre-read tile-0 kh0 fragments.
    STAGE_A(0); STAGE_B(0); STAGE_C(0); STAGE_D(0);
    STAGE_A(1); STAGE_B(1); STAGE_C(1);
    asm volatile("s_waitcnt vmcnt(10)" ::: "memory");
    __builtin_amdgcn_s_barrier();
#pragma unroll
    for (int i = 0; i < 4; ++i)
        fX0[i] = *(const i32x4*)((const char*)&sPa[0][0][0][0] + roA + i * 1024);
#pragma unroll
    for (int i = 0; i < 4; ++i)
        fpA[i] = *(const i32x4*)((const char*)&sPt[0][0][0][0] + roP + i * 1024);

    for (int kt = 0; kt < NT; ++kt) {
        const int buf = kt & 1;
        const char* bA1 = (const char*)&sPa[buf][1][0][0];
        const char* bB0 = (const char*)&sPb[buf][0][0][0];
        const char* bB1 = (const char*)&sPb[buf][1][0][0];
        const char* bP1 = (const char*)&sPt[buf][1][0][0];
        const char* nA0 = (const char*)&sPa[buf ^ 1][0][0][0];
        const char* nP0 = (const char*)&sPt[buf ^ 1][0][0][0];

        // -------- phase 1: accA x kh0 (uses fX0, fpA) --------
        __builtin_amdgcn_s_setprio(1);
        MFMA8(accA, fX0, fpA, 0);
        __builtin_amdgcn_s_setprio(0);
        if (kt < NT - 2) asm volatile("s_waitcnt vmcnt(6)" ::: "memory");
        else             asm volatile("s_waitcnt vmcnt(0)" ::: "memory");
#pragma unroll
        for (int i = 0; i < 4; ++i) fX1[i] = *(const i32x4*)(bB0 + roA + i * 1024);
        if (kt + 1 < NT) STAGE_D(kt + 1);
        __builtin_amdgcn_s_setprio(1);
        MFMA8(accA, fX0, fpA, 2);
        __builtin_amdgcn_s_setprio(0);
        __builtin_amdgcn_s_barrier();

        // -------- phase 2: accB x kh0 (uses fX1, fpA) --------
        __builtin_amdgcn_s_setprio(1);
        MFMA8(accB, fX1, fpA, 0);
        __builtin_amdgcn_s_setprio(0);
#pragma unroll
        for (int i = 0; i < 4; ++i) fX0[i] = *(const i32x4*)(bA1 + roA + i * 1024);
#pragma unroll
        for (int i = 0; i < 4; ++i) fpB[i] = *(const i32x4*)(bP1 + roP + i * 1024);
        if (kt + 2 < NT) STAGE_A(kt + 2);
        __builtin_amdgcn_s_setprio(1);
        MFMA8(accB, fX1, fpA, 2);
        __builtin_amdgcn_s_setprio(0);
        __builtin_amdgcn_s_barrier();

        // -------- phase 3: accA x kh1 (uses fX0, fpB) --------
        __builtin_amdgcn_s_setprio(1);
        MFMA8(accA, fX0, fpB, 0);
        __builtin_amdgcn_s_setprio(0);
        if (kt < NT - 2) asm volatile("s_waitcnt vmcnt(6)" ::: "memory");
        else             asm volatile("s_waitcnt vmcnt(0)" ::: "memory");
#pragma unroll
        for (int i = 0; i < 4; ++i) fX1[i] = *(const i32x4*)(bB1 + roA + i * 1024);
        if (kt + 2 < NT) STAGE_B(kt + 2);
        __builtin_amdgcn_s_setprio(1);
        MFMA8(accA, fX0, fpB, 2);
        __builtin_amdgcn_s_setprio(0);
        __builtin_amdgcn_s_barrier();

        // -------- phase 4: accB x kh1 (uses fX1, fpB) --------
        __builtin_amdgcn_s_setprio(1);
        MFMA8(accB, fX1, fpB, 0);
        __builtin_amdgcn_s_setprio(0);
#pragma unroll
        for (int i = 0; i < 4; ++i) fX0[i] = *(const i32x4*)(nA0 + roA + i * 1024);
#pragma unroll
        for (int i = 0; i < 4; ++i) fpA[i] = *(const i32x4*)(nP0 + roP + i * 1024);
        if (kt + 2 < NT) STAGE_C(kt + 2);
        __builtin_amdgcn_s_setprio(1);
        MFMA8(accB, fX1, fpB, 2);
        __builtin_amdgcn_s_setprio(0);
        __builtin_amdgcn_s_barrier();
    }

    // epilogue: dequant + gate polynomial
#pragma unroll
    for (int mi = 0; mi < 4; ++mi) {
#pragma unroll
        for (int i = 0; i < 4; ++i) {
            const int row = m0 + wr * 64 + mi * 16 + lq * 4 + i;
            const float4 c = C4[row];
            const float sa = SA[row];
            const float sb = SB[row];
#pragma unroll
            for (int ni = 0; ni < 4; ++ni) {
                const int col = n0 + wc * 64 + ni * 16 + lr;
                const float Av = (float)accA[mi][ni][i] * sa;
                const float Bv = (float)accB[mi][ni][i] * sb;
                out[(size_t)row * N_DIM + col] = c.x + c.y * Av + c.z * Bv + c.w * Av * Bv;
            }
        }
    }
}

extern "C" void kernel_launch(void* const* d_in, const int* in_sizes, int n_in,
                              void* d_out, int out_size, void* d_ws, size_t ws_size,
                              hipStream_t stream) {
    const float* prev = (const float*)d_in[0];   // [2048][8192]
    const float* Wa   = (const float*)d_in[1];   // [2048][2048]
    const float* Wb   = (const float*)d_in[2];   // [2048][2048]
    const float* TW   = (const float*)d_in[3];   // [16][2048]
    float* out = (float*)d_out;                  // [2048][8192]

    char* ws = (char*)d_ws;
    unsigned char* Pa = (unsigned char*)(ws);                       //  4 MiB
    unsigned char* Pb = (unsigned char*)(ws + (size_t)(4u << 20));  //  4 MiB
    unsigned char* Pt = (unsigned char*)(ws + (size_t)(8u << 20));  // 16 MiB
    float4* C4 = (float4*)(ws + (size_t)(24u << 20));               // 32 KiB
    float*  SA = (float*)(ws + (size_t)(24u << 20) + (32u << 10));  //  8 KiB
    float*  SB = (float*)(ws + (size_t)(24u << 20) + (64u << 10));  //  8 KiB

    softmax_rows_kernel<<<dim3(2048, 2), 256, 0, stream>>>(Wa, Wb, Pa, Pb, SA, SB);
    table_c_kernel<<<dim3(8), 256, 0, stream>>>(TW, C4);
    transp_conv_kernel<<<dim3(N_DIM / 64, K_DIM / 64), 256, 0, stream>>>(prev, Pt);
    logic_gemm_kernel<<<dim3(N_DIM / BN, M_DIM / BM), 512, 0, stream>>>(Pa, Pb, Pt, C4, SA, SB, out);
}

// Round 13
// 83.590 us; speedup vs baseline: 1.9639x; 1.0710x over previous
//
#include <hip/hip_runtime.h>
#include <hip/hip_bf16.h>

#define M_DIM 2048   // size
#define K_DIM 2048   // prev_size
#define N_DIM 8192   // batch

#define BM 128
#define BN 256
#define BK 128            // i8 elements per K-tile (two kh halves of 64)
#define NT (K_DIM / BK)   // 16 K-tiles

typedef __attribute__((ext_vector_type(4))) int i32x4;

// async global->LDS: each lane contributes 16B; LDS dest is wave-uniform base,
// hardware writes base + lane*16 (linear).
static __device__ __forceinline__ void stage1k(const unsigned char* g, void* l) {
    __builtin_amdgcn_global_load_lds(
        (const __attribute__((address_space(1))) void*)g,
        (__attribute__((address_space(3))) void*)l, 16, 0, 0);
}

// ---- fused preprocessing: transp+quant / row-softmax+quant / table-c -------
// blocks [0,4096): prev [K][N] f32 -> prevT [N][K] u8 (x127, transposed)
// blocks [4096,8192): softmax rows of Wa/Wb -> u8 probs + per-row scale
// blocks [8192,8200): table softmax -> C4 gate coefficients
__global__ __launch_bounds__(256) void prep_kernel(
    const float* __restrict__ prev, const float* __restrict__ Wa,
    const float* __restrict__ Wb, const float* __restrict__ TW,
    unsigned char* __restrict__ Pa, unsigned char* __restrict__ Pb,
    unsigned char* __restrict__ Pt,
    float* __restrict__ SA, float* __restrict__ SB, float4* __restrict__ C4)
{
    __shared__ unsigned char tile[64][80];
    __shared__ float redm[4], reds[4];
    const int bx = blockIdx.x;
    const int t = threadIdx.x;

    if (bx < 4096) {
        // ---- transpose + quantize (4x4 micro-block per thread) ----
        const int n0 = (bx & 127) * 64;
        const int k0 = (bx >> 7) * 64;
        const int kb = (t >> 4) * 4;
        const int nb = (t & 15) * 4;
        unsigned int pk0 = 0, pk1 = 0, pk2 = 0, pk3 = 0;
#pragma unroll
        for (int j = 0; j < 4; ++j) {
            float4 v = *(const float4*)(prev + (size_t)(k0 + kb + j) * N_DIM + n0 + nb);
            pk0 |= (unsigned int)(unsigned char)(int)(127.f * v.x + 0.5f) << (8 * j);
            pk1 |= (unsigned int)(unsigned char)(int)(127.f * v.y + 0.5f) << (8 * j);
            pk2 |= (unsigned int)(unsigned char)(int)(127.f * v.z + 0.5f) << (8 * j);
            pk3 |= (unsigned int)(unsigned char)(int)(127.f * v.w + 0.5f) << (8 * j);
        }
        *(unsigned int*)&tile[nb + 0][kb] = pk0;
        *(unsigned int*)&tile[nb + 1][kb] = pk1;
        *(unsigned int*)&tile[nb + 2][kb] = pk2;
        *(unsigned int*)&tile[nb + 3][kb] = pk3;
        __syncthreads();
        const int n = t >> 2;
        const int k16 = (t & 3) * 16;
        int4 v = *(const int4*)&tile[n][k16];
        *(int4*)(Pt + (size_t)(n0 + n) * K_DIM + k0 + k16) = v;
        return;
    }
    if (bx < 8192) {
        // ---- row softmax + u8 quant: a_k = round(127*exp(x-m)) ----
        const int r = bx - 4096;             // 0..4095
        const int row = r & 2047;
        const int isB = r >> 11;
        const float* W = isB ? Wb : Wa;
        unsigned char* P = isB ? Pb : Pa;
        float* S = isB ? SB : SA;
        const float* w = W + (size_t)row * K_DIM + t * 8;
        float4 v0 = *(const float4*)(w);
        float4 v1 = *(const float4*)(w + 4);
        float x[8] = {v0.x, v0.y, v0.z, v0.w, v1.x, v1.y, v1.z, v1.w};

        float m = x[0];
#pragma unroll
        for (int i = 1; i < 8; ++i) m = fmaxf(m, x[i]);
#pragma unroll
        for (int off = 32; off >= 1; off >>= 1) m = fmaxf(m, __shfl_xor(m, off));
        const int wid = t >> 6;
        if ((t & 63) == 0) redm[wid] = m;
        __syncthreads();
        m = fmaxf(fmaxf(redm[0], redm[1]), fmaxf(redm[2], redm[3]));

        float s = 0.f;
#pragma unroll
        for (int i = 0; i < 8; ++i) { x[i] = __expf(x[i] - m); s += x[i]; }
#pragma unroll
        for (int off = 32; off >= 1; off >>= 1) s += __shfl_xor(s, off);
        if ((t & 63) == 0) reds[wid] = s;
        __syncthreads();
        s = reds[0] + reds[1] + reds[2] + reds[3];

        union { unsigned char u[8]; int2 v; } pk;
#pragma unroll
        for (int i = 0; i < 8; ++i)
            pk.u[i] = (unsigned char)(int)(127.f * x[i] + 0.5f);
        *(int2*)(P + (size_t)row * K_DIM + t * 8) = pk.v;
        if (t == 0) S[row] = 1.f / (16129.f * s);
        return;
    }
    // ---- table softmax -> gate coefficients ----
    const int s = (bx - 8192) * 256 + t;
    if (s >= M_DIM) return;
    float x[16];
    float m = -1e30f;
#pragma unroll
    for (int tt = 0; tt < 16; ++tt) { x[tt] = TW[tt * M_DIM + s]; m = fmaxf(m, x[tt]); }
    float sum = 0.f;
#pragma unroll
    for (int tt = 0; tt < 16; ++tt) { x[tt] = __expf(x[tt] - m); sum += x[tt]; }
    const float inv = 1.0f / sum;
    const float c0a[16] = {0,0,0,0,0,0,0,0, 1,1,1,1,1,1,1,1};
    const float cAa[16] = {0,0,1,1,0,0,1,1, -1,-1,0,0,-1,-1,0,0};
    const float cBa[16] = {0,0,0,0,1,1,1,1, -1,-1,-1,-1,0,0,0,0};
    const float cXa[16] = {0,1,-1,0,-1,0,-2,-1, 1,2,0,1,0,1,-1,0};
    float c0 = 0.f, cA = 0.f, cB = 0.f, cX = 0.f;
#pragma unroll
    for (int tt = 0; tt < 16; ++tt) {
        const float p = x[tt] * inv;
        c0 += p * c0a[tt]; cA += p * cAa[tt]; cB += p * cBa[tt]; cX += p * cXa[tt];
    }
    C4[s] = make_float4(c0, cA, cB, cX);
}

// ------------- dual i8 GEMM, merged 2-phase schedule + gate epilogue --------
// Components verified through R12 (i8 quant, sigma(r)=(r>>1)&3 swizzle,
// stage1k, 16x16x64 i8 MFMA, 0 bank conflicts). Change vs R12: 4 phases/kt
// -> 2 phases/kt (halves barriers + guards). Frag sets double-buffered with
// STATIC names: set0 = {fa0,fb0,fp0} (kh0), set1 = {fa1,fb1,fp1} (kh1).
//
// Phase I(kt):  16 MFMA (set0) | reads set1 <- [buf][1] | stage C,D(kt+1)
//               (-> [buf^1][1]) | vmcnt(4) | 16 MFMA (set0) | barrier
// Phase II(kt): 16 MFMA (set1) | reads set0 <- [buf^1][0] | stage A,B(kt+2)
//               (-> [buf][0]) | vmcnt(4) | 16 MFMA (set1) | barrier
//
// WAR: C,D(kt+1) target last consumed start-II(kt-1) -> barrier end-II(kt-1)
// intervenes; A,B(kt+2) target last consumed start-I(kt) -> barrier end-I(kt)
// intervenes. Publishes (FIFO, 8 stage calls/kt): guard@I drains A,B(kt+1)
// (outstanding A,B(kt+1)+C,D(kt+1)=8 -> vmcnt(4)) for mid-II reads; guard@II
// drains C,D(kt+1) for mid-I(kt+1) reads. Tails: vmcnt(0).

#define MFMA8(ACC, FA, FP, MI0)                                                \
    _Pragma("unroll") for (int mi = (MI0); mi < (MI0) + 2; ++mi)               \
    _Pragma("unroll") for (int ni = 0; ni < 4; ++ni)                           \
        ACC[mi][ni] = __builtin_amdgcn_mfma_i32_16x16x64_i8(                   \
            FA[mi], FP[ni], ACC[mi][ni], 0, 0, 0);

#define STAGE_A(T) do { const int b_ = (T) & 1; const size_t o_ = (size_t)(T) * BK; \
    stage1k(gPa + o_,  &sPa[b_][0][wid * 16][0]);                              \
    stage1k(gPt0 + o_, &sPt[b_][0][wid * 16][0]); } while (0)
#define STAGE_B(T) do { const int b_ = (T) & 1; const size_t o_ = (size_t)(T) * BK; \
    stage1k(gPt1 + o_, &sPt[b_][0][128 + wid * 16][0]);                        \
    stage1k(gPb + o_,  &sPb[b_][0][wid * 16][0]); } while (0)
#define STAGE_C(T) do { const int b_ = (T) & 1; const size_t o_ = (size_t)(T) * BK + 64; \
    stage1k(gPa + o_,  &sPa[b_][1][wid * 16][0]);                              \
    stage1k(gPt0 + o_, &sPt[b_][1][wid * 16][0]); } while (0)
#define STAGE_D(T) do { const int b_ = (T) & 1; const size_t o_ = (size_t)(T) * BK + 64; \
    stage1k(gPt1 + o_, &sPt[b_][1][128 + wid * 16][0]);                        \
    stage1k(gPb + o_,  &sPb[b_][1][wid * 16][0]); } while (0)

#define RD_SET(FA, FB, FP, BA, BB, BP)                                         \
    _Pragma("unroll") for (int i = 0; i < 4; ++i)                              \
        FA[i] = *(const i32x4*)((BA) + roA + i * 1024);                        \
    _Pragma("unroll") for (int i = 0; i < 4; ++i)                              \
        FP[i] = *(const i32x4*)((BP) + roP + i * 1024);                        \
    _Pragma("unroll") for (int i = 0; i < 4; ++i)                              \
        FB[i] = *(const i32x4*)((BB) + roA + i * 1024);

__global__ __launch_bounds__(512, 2) void logic_gemm_kernel(
    const unsigned char* __restrict__ Pa,   // [M][K] u8
    const unsigned char* __restrict__ Pb,   // [M][K] u8
    const unsigned char* __restrict__ Pt,   // prevT [N][K] u8
    const float4* __restrict__ C4,          // [M]
    const float* __restrict__ SA,           // [M] dequant scales
    const float* __restrict__ SB,           // [M]
    float* __restrict__ out)                // [M][N]
{
    __shared__ unsigned char sPa[2][2][128][64];   // 32 KB
    __shared__ unsigned char sPb[2][2][128][64];   // 32 KB
    __shared__ unsigned char sPt[2][2][256][64];   // 64 KB

    const int m0 = blockIdx.y * BM;
    const int n0 = blockIdx.x * BN;
    const int t = threadIdx.x;
    const int wid = t >> 6, lane = t & 63;
    const int wr = wid >> 2, wc = wid & 3;   // 2M x 4N waves, 64x64 out each
    const int lq = lane >> 4, lr = lane & 15;

    // staging: lane -> region row (lane>>2), pre-swizzled source col (bytes)
    const int srow = lane >> 2;                               // 0..15
    const int scol = (((lane & 3) ^ ((lane >> 3) & 3)) << 4); // {0,16,32,48} B
    const unsigned char* gPa  = Pa + (size_t)(m0 + wid * 16 + srow) * K_DIM + scol;
    const unsigned char* gPb  = Pb + (size_t)(m0 + wid * 16 + srow) * K_DIM + scol;
    const unsigned char* gPt0 = Pt + (size_t)(n0 + wid * 16 + srow) * K_DIM + scol;
    const unsigned char* gPt1 = gPt0 + (size_t)128 * K_DIM;

    // ds_read byte offsets (swizzled): row*64 + 16*(lq ^ sigma(row)),
    // sigma(r) = (r>>1)&3 -> conflict-free (verified R4..R12)
    const int cswz = (lq ^ ((lr >> 1) & 3)) << 4;
    const int roA = (wr * 64 + lr) * 64 + cswz;   // within [128][64B] region
    const int roP = (wc * 64 + lr) * 64 + cswz;   // within [256][64B] region

    i32x4 accA[4][4] = {};
    i32x4 accB[4][4] = {};
    i32x4 fa0[4], fb0[4], fp0[4], fa1[4], fb1[4], fp1[4];

    // prologue: A,B(0), C,D(0), A,B(1) = 12 calls; drain tile 0 (8 calls),
    // leave A,B(1) in flight; barrier; read set0 <- tile0 kh0.
    STAGE_A(0); STAGE_B(0); STAGE_C(0); STAGE_D(0);
    STAGE_A(1); STAGE_B(1);
    asm volatile("s_waitcnt vmcnt(4)" ::: "memory");
    __builtin_amdgcn_s_barrier();
    RD_SET(fa0, fb0, fp0,
           (const char*)&sPa[0][0][0][0],
           (const char*)&sPb[0][0][0][0],
           (const char*)&sPt[0][0][0][0]);

    for (int kt = 0; kt < NT; ++kt) {
        const int buf = kt & 1;
        const char* bA1 = (const char*)&sPa[buf][1][0][0];
        const char* bB1 = (const char*)&sPb[buf][1][0][0];
        const char* bP1 = (const char*)&sPt[buf][1][0][0];
        const char* nA0 = (const char*)&sPa[buf ^ 1][0][0][0];
        const char* nB0 = (const char*)&sPb[buf ^ 1][0][0][0];
        const char* nP0 = (const char*)&sPt[buf ^ 1][0][0][0];

        // ---------------- phase I: kh0 (set0) ----------------
        __builtin_amdgcn_s_setprio(1);
        MFMA8(accA, fa0, fp0, 0);
        MFMA8(accA, fa0, fp0, 2);
        __builtin_amdgcn_s_setprio(0);
        RD_SET(fa1, fb1, fp1, bA1, bB1, bP1);          // tile kt kh1
        if (kt + 1 < NT) { STAGE_C(kt + 1); STAGE_D(kt + 1); }
        if (kt < NT - 1) asm volatile("s_waitcnt vmcnt(4)" ::: "memory");
        else             asm volatile("s_waitcnt vmcnt(0)" ::: "memory");
        __builtin_amdgcn_s_setprio(1);
        MFMA8(accB, fb0, fp0, 0);
        MFMA8(accB, fb0, fp0, 2);
        __builtin_amdgcn_s_setprio(0);
        __builtin_amdgcn_s_barrier();

        // ---------------- phase II: kh1 (set1) ----------------
        __builtin_amdgcn_s_setprio(1);
        MFMA8(accA, fa1, fp1, 0);
        MFMA8(accA, fa1, fp1, 2);
        __builtin_amdgcn_s_setprio(0);
        if (kt + 1 < NT) RD_SET(fa0, fb0, fp0, nA0, nB0, nP0);   // tile kt+1 kh0
        if (kt + 2 < NT) { STAGE_A(kt + 2); STAGE_B(kt + 2); }
        if (kt < NT - 2) asm volatile("s_waitcnt vmcnt(4)" ::: "memory");
        else             asm volatile("s_waitcnt vmcnt(0)" ::: "memory");
        __builtin_amdgcn_s_setprio(1);
        MFMA8(accB, fb1, fp1, 0);
        MFMA8(accB, fb1, fp1, 2);
        __builtin_amdgcn_s_setprio(0);
        __builtin_amdgcn_s_barrier();
    }

    // epilogue: dequant + gate polynomial
#pragma unroll
    for (int mi = 0; mi < 4; ++mi) {
#pragma unroll
        for (int i = 0; i < 4; ++i) {
            const int row = m0 + wr * 64 + mi * 16 + lq * 4 + i;
            const float4 c = C4[row];
            const float sa = SA[row];
            const float sb = SB[row];
#pragma unroll
            for (int ni = 0; ni < 4; ++ni) {
                const int col = n0 + wc * 64 + ni * 16 + lr;
                const float Av = (float)accA[mi][ni][i] * sa;
                const float Bv = (float)accB[mi][ni][i] * sb;
                out[(size_t)row * N_DIM + col] = c.x + c.y * Av + c.z * Bv + c.w * Av * Bv;
            }
        }
    }
}

extern "C" void kernel_launch(void* const* d_in, const int* in_sizes, int n_in,
                              void* d_out, int out_size, void* d_ws, size_t ws_size,
                              hipStream_t stream) {
    const float* prev = (const float*)d_in[0];   // [2048][8192]
    const float* Wa   = (const float*)d_in[1];   // [2048][2048]
    const float* Wb   = (const float*)d_in[2];   // [2048][2048]
    const float* TW   = (const float*)d_in[3];   // [16][2048]
    float* out = (float*)d_out;                  // [2048][8192]

    char* ws = (char*)d_ws;
    unsigned char* Pa = (unsigned char*)(ws);                       //  4 MiB
    unsigned char* Pb = (unsigned char*)(ws + (size_t)(4u << 20));  //  4 MiB
    unsigned char* Pt = (unsigned char*)(ws + (size_t)(8u << 20));  // 16 MiB
    float4* C4 = (float4*)(ws + (size_t)(24u << 20));               // 32 KiB
    float*  SA = (float*)(ws + (size_t)(24u << 20) + (32u << 10));  //  8 KiB
    float*  SB = (float*)(ws + (size_t)(24u << 20) + (64u << 10));  //  8 KiB

    prep_kernel<<<dim3(8200), 256, 0, stream>>>(prev, Wa, Wb, TW,
                                                Pa, Pb, Pt, SA, SB, C4);
    logic_gemm_kernel<<<dim3(N_DIM / BN, M_DIM / BM), 512, 0, stream>>>(Pa, Pb, Pt, C4, SA, SB, out);
}